// Round 11
// baseline (34.072 us; speedup 1.0000x reference)
//
#include <hip/hip_runtime.h>
#include <math.h>

// ---------------------------------------------------------------------------
// FraudDetectionHybrid: 4-qubit statevector sim, algebraically collapsed.
// THREE kernels:
//   K_A (1 block): constexpr-MT19937(42) gate seq -> U_post (built ONCE)
//   K_B (1024 blk, 2 THREADS PER ELEMENT): encoder product state, each thread
//       does 8 of 16 matvec rows (partner via shfl_xor), pk-packable float2
//       complex math, <Z_w> -> ez + 0.5-scaled block partials
//   K_C (512 blk): redundant partial reduce -> BN+Linear coefs -> out
//
// R1-R3: scratch pathologies (device MT19937 / runtime-indexed arrays) fixed
// via constexpr+templates. R4: dispatch ~0.5us. R5-R8: in-kernel grid barriers
// lose to dispatch boundaries. R9/R10: issue-side micro-opts ~1us each.
// R10 analysis: useful FLOPs = 1.7us @ 157TF, HBM = 2us, fixed ~5us, yet
// kernels ~19us -> <10% VALU efficiency -> LATENCY-bound at 2 waves/SIMD
// (25% occupancy). This round: 2 threads/element -> 4 waves/SIMD (50%),
// __launch_bounds__(256,4) caps VGPR at 128 so occupancy materializes.
// ---------------------------------------------------------------------------

// ==================== compile-time numpy RandomState(42) ====================
struct CGates {
  int kind[64];   // 0=RX 1=RY 2=RZ 3=CNOT 4=CRX 5=H 6=SX
  int w0[64];
  int w1[64];
  int pidx[64];   // >=0: rand_params idx; -1 none; -2 rx0; -3 ry0; -4 rz0; -5 crx0
  int ng;
};

constexpr unsigned int c_mt_next(unsigned int (&mt)[624], int& pos) {
  if (pos >= 624) {
    for (int i = 0; i < 624; ++i) {
      unsigned int y = (mt[i] & 0x80000000u) | (mt[(i + 1) % 624] & 0x7fffffffu);
      unsigned int v = mt[(i + 397) % 624] ^ (y >> 1);
      if (y & 1u) v ^= 0x9908b0dfu;
      mt[i] = v;
    }
    pos = 0;
  }
  unsigned int y = mt[pos++];
  y ^= y >> 11;
  y ^= (y << 7) & 0x9d2c5680u;
  y ^= (y << 15) & 0xefc60000u;
  y ^= y >> 18;
  return y;
}

constexpr CGates make_gates() {
  CGates gl{};
  unsigned int mt[624] = {};
  mt[0] = 42u;
  for (int i = 1; i < 624; ++i)
    mt[i] = 1812433253u * (mt[i - 1] ^ (mt[i - 1] >> 30)) + (unsigned int)i;
  int pos = 624;
  int ng = 0, p = 0;
  for (int op = 0; op < 50; ++op) {
    unsigned int k = c_mt_next(mt, pos) & 3u;   // randint(4): one draw, mask 3
    if (k < 3u) {
      unsigned int w = c_mt_next(mt, pos) & 3u; // wire
      gl.kind[ng] = (int)k; gl.w0[ng] = (int)w; gl.w1[ng] = 0;
      gl.pidx[ng] = p++;
      ++ng;
    } else {
      // choice(4,2,replace=False): Fisher-Yates descending, mask-rejection
      int arr[4] = {0, 1, 2, 3};
      { unsigned int j = c_mt_next(mt, pos) & 3u;
        int t = arr[3]; arr[3] = arr[j]; arr[j] = t; }
      { unsigned int j = c_mt_next(mt, pos) & 3u;
        while (j > 2u) j = c_mt_next(mt, pos) & 3u;
        int t = arr[2]; arr[2] = arr[j]; arr[j] = t; }
      { unsigned int j = c_mt_next(mt, pos) & 1u;
        int t = arr[1]; arr[1] = arr[j]; arr[j] = t; }
      gl.kind[ng] = 3; gl.w0[ng] = arr[0]; gl.w1[ng] = arr[1]; gl.pidx[ng] = -1;
      ++ng;
    }
  }
  // trainable block
  gl.kind[ng] = 0; gl.w0[ng] = 0; gl.w1[ng] = 0; gl.pidx[ng] = -2; ++ng; // RX w0
  gl.kind[ng] = 1; gl.w0[ng] = 1; gl.w1[ng] = 0; gl.pidx[ng] = -3; ++ng; // RY w1
  gl.kind[ng] = 2; gl.w0[ng] = 3; gl.w1[ng] = 0; gl.pidx[ng] = -4; ++ng; // RZ w3
  gl.kind[ng] = 4; gl.w0[ng] = 0; gl.w1[ng] = 2; gl.pidx[ng] = -5; ++ng; // CRX(0,2)
  gl.kind[ng] = 5; gl.w0[ng] = 3; gl.w1[ng] = 0; gl.pidx[ng] = -1; ++ng; // H w3
  gl.kind[ng] = 6; gl.w0[ng] = 2; gl.w1[ng] = 0; gl.pidx[ng] = -1; ++ng; // SX w2
  gl.kind[ng] = 3; gl.w0[ng] = 3; gl.w1[ng] = 0; gl.pidx[ng] = -1; ++ng; // CNOT(3,0)
  gl.ng = ng;
  return gl;
}

inline constexpr CGates GL = make_gates();

inline constexpr int CK1 = GL.ng / 4;
inline constexpr int CK2 = GL.ng / 2;
inline constexpr int CK3 = (3 * GL.ng) / 4;

// ================= templated gate appliers (static indices) =================
// wire0 = MSB (bit 3): TB = 8 >> wire.

template <int TB>
__device__ __forceinline__ void ap_rx(float (&sx)[16], float (&sy)[16],
                                      float c, float s) {
#pragma unroll
  for (int i = 0; i < 16; ++i) {
    if (i & TB) continue;
    const int j = i | TB;
    float ax = sx[i], ay = sy[i], bx = sx[j], by = sy[j];
    sx[i] = c * ax + s * by;  sy[i] = c * ay - s * bx;
    sx[j] = c * bx + s * ay;  sy[j] = c * by - s * ax;
  }
}

template <int TB>
__device__ __forceinline__ void ap_ry(float (&sx)[16], float (&sy)[16],
                                      float c, float s) {
#pragma unroll
  for (int i = 0; i < 16; ++i) {
    if (i & TB) continue;
    const int j = i | TB;
    float ax = sx[i], ay = sy[i], bx = sx[j], by = sy[j];
    sx[i] = c * ax - s * bx;  sy[i] = c * ay - s * by;
    sx[j] = s * ax + c * bx;  sy[j] = s * ay + c * by;
  }
}

template <int TB>
__device__ __forceinline__ void ap_rz(float (&sx)[16], float (&sy)[16],
                                      float c, float s) {
#pragma unroll
  for (int i = 0; i < 16; ++i) {
    if (i & TB) continue;
    const int j = i | TB;
    float ax = sx[i], ay = sy[i], bx = sx[j], by = sy[j];
    sx[i] = c * ax + s * ay;  sy[i] = c * ay - s * ax;
    sx[j] = c * bx - s * by;  sy[j] = c * by + s * bx;
  }
}

template <int TB>
__device__ __forceinline__ void ap_h(float (&sx)[16], float (&sy)[16]) {
  const float r = 0.70710678118654752f;
#pragma unroll
  for (int i = 0; i < 16; ++i) {
    if (i & TB) continue;
    const int j = i | TB;
    float ax = sx[i], ay = sy[i], bx = sx[j], by = sy[j];
    sx[i] = r * (ax + bx);  sy[i] = r * (ay + by);
    sx[j] = r * (ax - bx);  sy[j] = r * (ay - by);
  }
}

template <int TB>
__device__ __forceinline__ void ap_sxg(float (&sx)[16], float (&sy)[16]) {
#pragma unroll
  for (int i = 0; i < 16; ++i) {
    if (i & TB) continue;
    const int j = i | TB;
    float ax = sx[i], ay = sy[i], bx = sx[j], by = sy[j];
    sx[i] = 0.5f * (ax - ay + bx + by);  sy[i] = 0.5f * (ay + ax + by - bx);
    sx[j] = 0.5f * (ax + ay + bx - by);  sy[j] = 0.5f * (ay - ax + by + bx);
  }
}

template <int CB, int TB>
__device__ __forceinline__ void ap_cnot(float (&sx)[16], float (&sy)[16]) {
#pragma unroll
  for (int i = 0; i < 16; ++i) {
    if (!(i & CB) || (i & TB)) continue;
    const int j = i | TB;
    float tx = sx[i], ty = sy[i];
    sx[i] = sx[j]; sy[i] = sy[j];
    sx[j] = tx;    sy[j] = ty;
  }
}

template <int CB, int TB>
__device__ __forceinline__ void ap_crx(float (&sx)[16], float (&sy)[16],
                                       float c, float s) {
#pragma unroll
  for (int i = 0; i < 16; ++i) {
    if (!(i & CB) || (i & TB)) continue;
    const int j = i | TB;
    float ax = sx[i], ay = sy[i], bx = sx[j], by = sy[j];
    sx[i] = c * ax + s * by;  sy[i] = c * ay - s * bx;
    sx[j] = c * bx + s * ay;  sy[j] = c * by - s * ax;
  }
}

// ============== compile-time-unrolled gate chain over [G, GEND) =============
template <int G, int GEND>
__device__ __forceinline__ void apply_range(
    float (&sx)[16], float (&sy)[16], const float* __restrict__ rp,
    const float* __restrict__ rx0, const float* __restrict__ ry0,
    const float* __restrict__ rz0, const float* __restrict__ crx0) {
  if constexpr (G < GEND) {
    constexpr int kind = GL.kind[G];
    constexpr int TB0 = 8 >> GL.w0[G];
    constexpr int TB1 = 8 >> GL.w1[G];
    constexpr int pi = GL.pidx[G];
    float c = 0.f, s = 0.f;
    if constexpr (kind == 0 || kind == 1 || kind == 2 || kind == 4) {
      float th;
      if constexpr (pi >= 0)       th = rp[pi];
      else if constexpr (pi == -2) th = rx0[0];
      else if constexpr (pi == -3) th = ry0[0];
      else if constexpr (pi == -4) th = rz0[0];
      else                         th = crx0[0];
      float h = 0.5f * th;
      s = __sinf(h);
      c = __cosf(h);
    }
    if constexpr (kind == 0)      ap_rx<TB0>(sx, sy, c, s);
    else if constexpr (kind == 1) ap_ry<TB0>(sx, sy, c, s);
    else if constexpr (kind == 2) ap_rz<TB0>(sx, sy, c, s);
    else if constexpr (kind == 3) ap_cnot<TB0, TB1>(sx, sy);
    else if constexpr (kind == 4) ap_crx<TB0, TB1>(sx, sy, c, s);
    else if constexpr (kind == 5) ap_h<TB0>(sx, sy);
    else                          ap_sxg<TB0>(sx, sy);
    apply_range<G + 1, GEND>(sx, sy, rp, rx0, ry0, rz0, crx0);
  }
}

// ===================== per-element helpers ==================================
__device__ __forceinline__ void phase1(const float* __restrict__ features,
                                       long long b, float (&t01x)[4],
                                       float (&t01y)[4], float (&t23x)[4],
                                       float (&t23y)[4]) {
  const float4* fp = (const float4*)(features + b * 16);
  float4 F0 = fp[0], F1 = fp[1], F2 = fp[2], F3 = fp[3];
  float L0[4] = {F0.x, F0.y, F0.z, F0.w};
  float L1[4] = {F1.x, F1.y, F1.z, F1.w};
  float L2[4] = {F2.x, F2.y, F2.z, F2.w};
  float L3[4] = {F3.x, F3.y, F3.z, F3.w};
  float vax[4], vay[4], vbx[4], vby[4];
#pragma unroll
  for (int w = 0; w < 4; ++w) {
    float h0 = 0.5f * L0[w], h1 = 0.5f * L1[w];
    float h2 = 0.5f * L2[w], h3 = 0.5f * L3[w];
    float s0 = __sinf(h0), c0 = __cosf(h0);
    float s1 = __sinf(h1), c1 = __cosf(h1);
    float s2 = __sinf(h2), c2 = __cosf(h2);
    float s3 = __sinf(h3), c3 = __cosf(h3);
    float ax = c0 * c1, ay = -c0 * s1;
    float bx = s0 * c1, by = s0 * s1;
    float a2x = c2 * ax + s2 * by, a2y = c2 * ay - s2 * bx;
    float b2x = s2 * ay + c2 * bx, b2y = -s2 * ax + c2 * by;
    vax[w] = c3 * a2x - s3 * b2x; vay[w] = c3 * a2y - s3 * b2y;
    vbx[w] = s3 * a2x + c3 * b2x; vby[w] = s3 * a2y + c3 * b2y;
  }
  t01x[0] = vax[0] * vax[1] - vay[0] * vay[1]; t01y[0] = vax[0] * vay[1] + vay[0] * vax[1];
  t01x[1] = vax[0] * vbx[1] - vay[0] * vby[1]; t01y[1] = vax[0] * vby[1] + vay[0] * vbx[1];
  t01x[2] = vbx[0] * vax[1] - vby[0] * vay[1]; t01y[2] = vbx[0] * vay[1] + vby[0] * vax[1];
  t01x[3] = vbx[0] * vbx[1] - vby[0] * vby[1]; t01y[3] = vbx[0] * vby[1] + vby[0] * vbx[1];
  t23x[0] = vax[2] * vax[3] - vay[2] * vay[3]; t23y[0] = vax[2] * vay[3] + vay[2] * vax[3];
  t23x[1] = vax[2] * vbx[3] - vay[2] * vby[3]; t23y[1] = vax[2] * vby[3] + vay[2] * vbx[3];
  t23x[2] = vbx[2] * vax[3] - vby[2] * vay[3]; t23y[2] = vbx[2] * vay[3] + vby[2] * vax[3];
  t23x[3] = vbx[2] * vbx[3] - vby[2] * vby[3]; t23y[3] = vbx[2] * vby[3] + vby[2] * vbx[3];
}

// full-element phase2 (used by K_C fallback only)
__device__ __forceinline__ void phase2_full(const float4* __restrict__ U4,
                                            const float (&t01x)[4], const float (&t01y)[4],
                                            const float (&t23x)[4], const float (&t23y)[4],
                                            float (&ez)[4]) {
  float sx[16], sy[16];
#pragma unroll
  for (int i = 0; i < 16; ++i) {
    int a = i >> 2, c = i & 3;
    sx[i] = t01x[a] * t23x[c] - t01y[a] * t23y[c];
    sy[i] = t01x[a] * t23y[c] + t01y[a] * t23x[c];
  }
  float e0 = 0.f, e1 = 0.f, e2 = 0.f, e3 = 0.f;
#pragma unroll
  for (int i = 0; i < 16; ++i) {
    float ax = 0.f, ay = 0.f;
#pragma unroll
    for (int j2 = 0; j2 < 8; ++j2) {
      float4 u = U4[i * 8 + j2];
      int j = 2 * j2;
      ax += u.x * sx[j] - u.y * sy[j] + u.z * sx[j + 1] - u.w * sy[j + 1];
      ay += u.x * sy[j] + u.y * sx[j] + u.z * sy[j + 1] + u.w * sx[j + 1];
    }
    float p = ax * ax + ay * ay;
    e0 += (i & 8) ? -p : p;
    e1 += (i & 4) ? -p : p;
    e2 += (i & 2) ? -p : p;
    e3 += (i & 1) ? -p : p;
  }
  ez[0] = e0; ez[1] = e1; ez[2] = e2; ez[3] = e3;
}

// =================== K_A: build U once (1 block, 4 waves) ===================
__global__ __launch_bounds__(256) void build_u_kernel(
    const float* __restrict__ rand_params, const float* __restrict__ rx0,
    const float* __restrict__ ry0, const float* __restrict__ rz0,
    const float* __restrict__ crx0, float2* __restrict__ U_out) {
  __shared__ float2 chunks[4][256];
  __shared__ float2 comb[2][256];
  int tid = threadIdx.x;
  int wv = tid >> 6, lane = tid & 63;

  if (lane < 16) {
    float sx[16], sy[16];
#pragma unroll
    for (int i = 0; i < 16; ++i) { sx[i] = (i == lane) ? 1.f : 0.f; sy[i] = 0.f; }
    if (wv == 0)      apply_range<0,   CK1  >(sx, sy, rand_params, rx0, ry0, rz0, crx0);
    else if (wv == 1) apply_range<CK1, CK2  >(sx, sy, rand_params, rx0, ry0, rz0, crx0);
    else if (wv == 2) apply_range<CK2, CK3  >(sx, sy, rand_params, rx0, ry0, rz0, crx0);
    else              apply_range<CK3, GL.ng>(sx, sy, rand_params, rx0, ry0, rz0, crx0);
#pragma unroll
    for (int i = 0; i < 16; ++i)
      chunks[wv][i * 16 + lane] = make_float2(sx[i], sy[i]);
  }
  __syncthreads();

  {
    int r = tid >> 4, c = tid & 15;
    float xr = 0.f, xi = 0.f, yr = 0.f, yi = 0.f;
#pragma unroll
    for (int k = 0; k < 16; ++k) {
      float2 g1 = chunks[1][r * 16 + k], g0 = chunks[0][k * 16 + c];
      xr += g1.x * g0.x - g1.y * g0.y;  xi += g1.x * g0.y + g1.y * g0.x;
      float2 g3 = chunks[3][r * 16 + k], g2 = chunks[2][k * 16 + c];
      yr += g3.x * g2.x - g3.y * g2.y;  yi += g3.x * g2.y + g3.y * g2.x;
    }
    comb[0][r * 16 + c] = make_float2(xr, xi);
    comb[1][r * 16 + c] = make_float2(yr, yi);
  }
  __syncthreads();

  {
    int r = tid >> 4, c = tid & 15;
    float ur = 0.f, ui = 0.f;
#pragma unroll
    for (int k = 0; k < 16; ++k) {
      float2 a = comb[1][r * 16 + k], d = comb[0][k * 16 + c];
      ur += a.x * d.x - a.y * d.y;
      ui += a.x * d.y + a.y * d.x;
    }
    U_out[r * 16 + c] = make_float2(ur, ui);
  }
}

// ====== K_B: 2 threads/element; each does 8 matvec rows; 4 waves/SIMD =======
__global__ __launch_bounds__(256, 4) void main_kernel(
    const float* __restrict__ features, const float4* __restrict__ U4,
    float* __restrict__ ez_out, float* __restrict__ partials, int B, int useEz) {
  __shared__ float wred[4][8];
  int tid = threadIdx.x;
  int half = tid & 1;
  long long e = (long long)blockIdx.x * 128 + (tid >> 1);
  bool valid = e < B;

  float ez[4] = {0.f, 0.f, 0.f, 0.f};
  if (valid) {
    float t01x[4], t01y[4], t23x[4], t23y[4];
    phase1(features, e, t01x, t01y, t23x, t23y);
    // sv = s (complex), nv = i-rotated (-im, re) for pk-packable complex FMA
    float2 sv[16], nv[16];
#pragma unroll
    for (int i = 0; i < 16; ++i) {
      int a = i >> 2, c = i & 3;
      float sxv = t01x[a] * t23x[c] - t01y[a] * t23y[c];
      float syv = t01x[a] * t23y[c] + t01y[a] * t23x[c];
      sv[i] = make_float2(sxv, syv);
      nv[i] = make_float2(-syv, sxv);
    }
    int rbase = half * 8;
#pragma unroll
    for (int r = 0; r < 8; ++r) {
      int i = rbase + r;
      float2 a = make_float2(0.f, 0.f);
#pragma unroll
      for (int j2 = 0; j2 < 8; ++j2) {
        float4 u = U4[i * 8 + j2];          // (re0, im0, re1, im1), uniform
        int j = 2 * j2;
        a = a + sv[j] * u.x + nv[j] * u.y + sv[j + 1] * u.z + nv[j + 1] * u.w;
      }
      float p = a.x * a.x + a.y * a.y;
      ez[0] += (i & 8) ? -p : p;
      ez[1] += (i & 4) ? -p : p;
      ez[2] += (i & 2) ? -p : p;
      ez[3] += (i & 1) ? -p : p;
    }
  }
  // partner combine: both threads now hold the full element ez
#pragma unroll
  for (int k = 0; k < 4; ++k) ez[k] += __shfl_xor(ez[k], 1, 64);
  if (valid && useEz && half == 0)
    ((float4*)ez_out)[e] = make_float4(ez[0], ez[1], ez[2], ez[3]);

  // block partials: each element counted twice -> scale 0.5 (exact)
  float q[8] = {ez[0], ez[1], ez[2], ez[3],
                ez[0] * ez[0], ez[1] * ez[1], ez[2] * ez[2], ez[3] * ez[3]};
#pragma unroll
  for (int off = 32; off; off >>= 1)
#pragma unroll
    for (int k = 0; k < 8; ++k) q[k] += __shfl_down(q[k], off, 64);
  int lane = tid & 63, wv = tid >> 6;
  if (lane == 0)
#pragma unroll
    for (int k = 0; k < 8; ++k) wred[wv][k] = q[k];
  __syncthreads();
  if (tid == 0) {
#pragma unroll
    for (int k = 0; k < 8; ++k)
      partials[(size_t)blockIdx.x * 8 + k] =
          0.5f * (wred[0][k] + wred[1][k] + wred[2][k] + wred[3][k]);
  }
}

// ========= K_C: redundant stats reduce -> coefs -> output pass ==============
__global__ __launch_bounds__(256) void out_kernel(
    const float* __restrict__ partials, int nblk,
    const float* __restrict__ gamma, const float* __restrict__ beta,
    const float* __restrict__ W, const float* __restrict__ bias,
    const float* __restrict__ ez_in, const float* __restrict__ features,
    const float4* __restrict__ U4, float* __restrict__ out,
    int B, int useEz, float invB) {
  __shared__ float wred[4][8];
  __shared__ float coefs[5];
  int tid = threadIdx.x;

  float q[8] = {0.f, 0.f, 0.f, 0.f, 0.f, 0.f, 0.f, 0.f};
  for (int idx = tid; idx < nblk; idx += 256) {
    const float4* p4 = (const float4*)(partials + (size_t)idx * 8);
    float4 A = p4[0], Bq = p4[1];
    q[0] += A.x;  q[1] += A.y;  q[2] += A.z;  q[3] += A.w;
    q[4] += Bq.x; q[5] += Bq.y; q[6] += Bq.z; q[7] += Bq.w;
  }
#pragma unroll
  for (int off = 32; off; off >>= 1)
#pragma unroll
    for (int k = 0; k < 8; ++k) q[k] += __shfl_down(q[k], off, 64);
  int lane = tid & 63, wv = tid >> 6;
  if (lane == 0)
#pragma unroll
    for (int k = 0; k < 8; ++k) wred[wv][k] = q[k];
  __syncthreads();
  if (tid == 0) {
    float c0 = bias[0];
#pragma unroll
    for (int w = 0; w < 4; ++w) {
      float Sw = wred[0][w] + wred[1][w] + wred[2][w] + wred[3][w];
      float Qw = wred[0][4 + w] + wred[1][4 + w] + wred[2][4 + w] + wred[3][4 + w];
      float mu = Sw * invB;
      float var = Qw * invB - mu * mu;
      float inv = rsqrtf(var + 1e-5f);
      coefs[w] = W[w] * gamma[w] * inv;
      c0 += W[w] * (beta[w] - gamma[w] * mu * inv);
    }
    coefs[4] = c0;
  }
  __syncthreads();

  long long b = (long long)blockIdx.x * 256 + tid;
  if (b >= B) return;
  float ez[4];
  if (useEz) {
    float4 e = ((const float4*)ez_in)[b];
    ez[0] = e.x; ez[1] = e.y; ez[2] = e.z; ez[3] = e.w;
  } else {
    float t01x[4], t01y[4], t23x[4], t23y[4];
    phase1(features, b, t01x, t01y, t23x, t23y);
    phase2_full(U4, t01x, t01y, t23x, t23y, ez);
  }
  out[b] = coefs[4] + coefs[0] * ez[0] + coefs[1] * ez[1] +
           coefs[2] * ez[2] + coefs[3] * ez[3];
}

// ================================ launch ====================================
extern "C" void kernel_launch(void* const* d_in, const int* in_sizes, int n_in,
                              void* d_out, int out_size, void* d_ws, size_t ws_size,
                              hipStream_t stream) {
  const float* features    = (const float*)d_in[0];
  const float* rand_params = (const float*)d_in[1];
  const float* rx0         = (const float*)d_in[2];
  const float* ry0         = (const float*)d_in[3];
  const float* rz0         = (const float*)d_in[4];
  const float* crx0        = (const float*)d_in[5];
  const float* gamma       = (const float*)d_in[6];
  const float* beta        = (const float*)d_in[7];
  const float* W           = (const float*)d_in[8];
  const float* bias        = (const float*)d_in[9];
  float* out = (float*)d_out;

  int B = in_sizes[0] / 16;
  int nblkB = (B + 127) / 128;   // 2 threads per element
  int nblkC = (B + 255) / 256;

  char* ws = (char*)d_ws;
  float2* U = (float2*)ws;                                    // 2048 B
  float* partials = (float*)(ws + 2048);                      // nblkB*32 B
  size_t ez_off = (2048 + (size_t)nblkB * 32 + 255) & ~(size_t)255;
  float* ez = (float*)(ws + ez_off);
  int useEz = (ws_size >= ez_off + (size_t)B * 16) ? 1 : 0;

  build_u_kernel<<<1, 256, 0, stream>>>(rand_params, rx0, ry0, rz0, crx0, U);
  main_kernel<<<nblkB, 256, 0, stream>>>(features, (const float4*)U, ez,
                                         partials, B, useEz);
  out_kernel<<<nblkC, 256, 0, stream>>>(partials, nblkB, gamma, beta, W, bias,
                                        ez, features, (const float4*)U, out,
                                        B, useEz, 1.0f / (float)B);
}

// Round 12
// 22.568 us; speedup vs baseline: 1.5097x; 1.5097x over previous
//
#include <hip/hip_runtime.h>
#include <math.h>

// ---------------------------------------------------------------------------
// FraudDetectionHybrid: 4-qubit statevector sim, algebraically collapsed.
// THREE kernels:
//   K_A (1 block): constexpr-MT19937(42) gate seq -> U_post (built ONCE)
//   K_B (512 blk, 1 thread/element): encoder product state; 16x16 complex
//       matvec with float2 PK-packed FMAs (v_pk_fma_f32), 2 accumulators/row,
//       U read via wave-uniform s_load; <Z_w> -> ez + block partials
//   K_C (512 blk): redundant partial reduce -> BN+Linear coefs -> out
//
// R1-R3: scratch pathologies fixed (constexpr gates + templated appliers).
// R4: dispatch ~0.5us. R5-R8: in-kernel grid barriers lose to dispatch
// boundaries. R9/R10: native trig + s_load-uniform U (~1us each).
// R11 LESSON: 2-thread/element split regressed +10us — it broke s_load
// uniformity (lane-dependent row base) and (256,4) likely spilled VGPRs.
// The pk-float2 matvec ingredient was never cleanly tested -> this round:
// R10 structure + pk matvec only, no VGPR cap, uniform U rows.
// ---------------------------------------------------------------------------

// ==================== compile-time numpy RandomState(42) ====================
struct CGates {
  int kind[64];   // 0=RX 1=RY 2=RZ 3=CNOT 4=CRX 5=H 6=SX
  int w0[64];
  int w1[64];
  int pidx[64];   // >=0: rand_params idx; -1 none; -2 rx0; -3 ry0; -4 rz0; -5 crx0
  int ng;
};

constexpr unsigned int c_mt_next(unsigned int (&mt)[624], int& pos) {
  if (pos >= 624) {
    for (int i = 0; i < 624; ++i) {
      unsigned int y = (mt[i] & 0x80000000u) | (mt[(i + 1) % 624] & 0x7fffffffu);
      unsigned int v = mt[(i + 397) % 624] ^ (y >> 1);
      if (y & 1u) v ^= 0x9908b0dfu;
      mt[i] = v;
    }
    pos = 0;
  }
  unsigned int y = mt[pos++];
  y ^= y >> 11;
  y ^= (y << 7) & 0x9d2c5680u;
  y ^= (y << 15) & 0xefc60000u;
  y ^= y >> 18;
  return y;
}

constexpr CGates make_gates() {
  CGates gl{};
  unsigned int mt[624] = {};
  mt[0] = 42u;
  for (int i = 1; i < 624; ++i)
    mt[i] = 1812433253u * (mt[i - 1] ^ (mt[i - 1] >> 30)) + (unsigned int)i;
  int pos = 624;
  int ng = 0, p = 0;
  for (int op = 0; op < 50; ++op) {
    unsigned int k = c_mt_next(mt, pos) & 3u;   // randint(4): one draw, mask 3
    if (k < 3u) {
      unsigned int w = c_mt_next(mt, pos) & 3u; // wire
      gl.kind[ng] = (int)k; gl.w0[ng] = (int)w; gl.w1[ng] = 0;
      gl.pidx[ng] = p++;
      ++ng;
    } else {
      // choice(4,2,replace=False): Fisher-Yates descending, mask-rejection
      int arr[4] = {0, 1, 2, 3};
      { unsigned int j = c_mt_next(mt, pos) & 3u;
        int t = arr[3]; arr[3] = arr[j]; arr[j] = t; }
      { unsigned int j = c_mt_next(mt, pos) & 3u;
        while (j > 2u) j = c_mt_next(mt, pos) & 3u;
        int t = arr[2]; arr[2] = arr[j]; arr[j] = t; }
      { unsigned int j = c_mt_next(mt, pos) & 1u;
        int t = arr[1]; arr[1] = arr[j]; arr[j] = t; }
      gl.kind[ng] = 3; gl.w0[ng] = arr[0]; gl.w1[ng] = arr[1]; gl.pidx[ng] = -1;
      ++ng;
    }
  }
  // trainable block
  gl.kind[ng] = 0; gl.w0[ng] = 0; gl.w1[ng] = 0; gl.pidx[ng] = -2; ++ng; // RX w0
  gl.kind[ng] = 1; gl.w0[ng] = 1; gl.w1[ng] = 0; gl.pidx[ng] = -3; ++ng; // RY w1
  gl.kind[ng] = 2; gl.w0[ng] = 3; gl.w1[ng] = 0; gl.pidx[ng] = -4; ++ng; // RZ w3
  gl.kind[ng] = 4; gl.w0[ng] = 0; gl.w1[ng] = 2; gl.pidx[ng] = -5; ++ng; // CRX(0,2)
  gl.kind[ng] = 5; gl.w0[ng] = 3; gl.w1[ng] = 0; gl.pidx[ng] = -1; ++ng; // H w3
  gl.kind[ng] = 6; gl.w0[ng] = 2; gl.w1[ng] = 0; gl.pidx[ng] = -1; ++ng; // SX w2
  gl.kind[ng] = 3; gl.w0[ng] = 3; gl.w1[ng] = 0; gl.pidx[ng] = -1; ++ng; // CNOT(3,0)
  gl.ng = ng;
  return gl;
}

inline constexpr CGates GL = make_gates();

inline constexpr int CK1 = GL.ng / 4;
inline constexpr int CK2 = GL.ng / 2;
inline constexpr int CK3 = (3 * GL.ng) / 4;

// ================= templated gate appliers (static indices) =================
// wire0 = MSB (bit 3): TB = 8 >> wire.

template <int TB>
__device__ __forceinline__ void ap_rx(float (&sx)[16], float (&sy)[16],
                                      float c, float s) {
#pragma unroll
  for (int i = 0; i < 16; ++i) {
    if (i & TB) continue;
    const int j = i | TB;
    float ax = sx[i], ay = sy[i], bx = sx[j], by = sy[j];
    sx[i] = c * ax + s * by;  sy[i] = c * ay - s * bx;
    sx[j] = c * bx + s * ay;  sy[j] = c * by - s * ax;
  }
}

template <int TB>
__device__ __forceinline__ void ap_ry(float (&sx)[16], float (&sy)[16],
                                      float c, float s) {
#pragma unroll
  for (int i = 0; i < 16; ++i) {
    if (i & TB) continue;
    const int j = i | TB;
    float ax = sx[i], ay = sy[i], bx = sx[j], by = sy[j];
    sx[i] = c * ax - s * bx;  sy[i] = c * ay - s * by;
    sx[j] = s * ax + c * bx;  sy[j] = s * ay + c * by;
  }
}

template <int TB>
__device__ __forceinline__ void ap_rz(float (&sx)[16], float (&sy)[16],
                                      float c, float s) {
#pragma unroll
  for (int i = 0; i < 16; ++i) {
    if (i & TB) continue;
    const int j = i | TB;
    float ax = sx[i], ay = sy[i], bx = sx[j], by = sy[j];
    sx[i] = c * ax + s * ay;  sy[i] = c * ay - s * ax;
    sx[j] = c * bx - s * by;  sy[j] = c * by + s * bx;
  }
}

template <int TB>
__device__ __forceinline__ void ap_h(float (&sx)[16], float (&sy)[16]) {
  const float r = 0.70710678118654752f;
#pragma unroll
  for (int i = 0; i < 16; ++i) {
    if (i & TB) continue;
    const int j = i | TB;
    float ax = sx[i], ay = sy[i], bx = sx[j], by = sy[j];
    sx[i] = r * (ax + bx);  sy[i] = r * (ay + by);
    sx[j] = r * (ax - bx);  sy[j] = r * (ay - by);
  }
}

template <int TB>
__device__ __forceinline__ void ap_sxg(float (&sx)[16], float (&sy)[16]) {
#pragma unroll
  for (int i = 0; i < 16; ++i) {
    if (i & TB) continue;
    const int j = i | TB;
    float ax = sx[i], ay = sy[i], bx = sx[j], by = sy[j];
    sx[i] = 0.5f * (ax - ay + bx + by);  sy[i] = 0.5f * (ay + ax + by - bx);
    sx[j] = 0.5f * (ax + ay + bx - by);  sy[j] = 0.5f * (ay - ax + by + bx);
  }
}

template <int CB, int TB>
__device__ __forceinline__ void ap_cnot(float (&sx)[16], float (&sy)[16]) {
#pragma unroll
  for (int i = 0; i < 16; ++i) {
    if (!(i & CB) || (i & TB)) continue;
    const int j = i | TB;
    float tx = sx[i], ty = sy[i];
    sx[i] = sx[j]; sy[i] = sy[j];
    sx[j] = tx;    sy[j] = ty;
  }
}

template <int CB, int TB>
__device__ __forceinline__ void ap_crx(float (&sx)[16], float (&sy)[16],
                                       float c, float s) {
#pragma unroll
  for (int i = 0; i < 16; ++i) {
    if (!(i & CB) || (i & TB)) continue;
    const int j = i | TB;
    float ax = sx[i], ay = sy[i], bx = sx[j], by = sy[j];
    sx[i] = c * ax + s * by;  sy[i] = c * ay - s * bx;
    sx[j] = c * bx + s * ay;  sy[j] = c * by - s * ax;
  }
}

// ============== compile-time-unrolled gate chain over [G, GEND) =============
template <int G, int GEND>
__device__ __forceinline__ void apply_range(
    float (&sx)[16], float (&sy)[16], const float* __restrict__ rp,
    const float* __restrict__ rx0, const float* __restrict__ ry0,
    const float* __restrict__ rz0, const float* __restrict__ crx0) {
  if constexpr (G < GEND) {
    constexpr int kind = GL.kind[G];
    constexpr int TB0 = 8 >> GL.w0[G];
    constexpr int TB1 = 8 >> GL.w1[G];
    constexpr int pi = GL.pidx[G];
    float c = 0.f, s = 0.f;
    if constexpr (kind == 0 || kind == 1 || kind == 2 || kind == 4) {
      float th;
      if constexpr (pi >= 0)       th = rp[pi];
      else if constexpr (pi == -2) th = rx0[0];
      else if constexpr (pi == -3) th = ry0[0];
      else if constexpr (pi == -4) th = rz0[0];
      else                         th = crx0[0];
      float h = 0.5f * th;
      s = __sinf(h);
      c = __cosf(h);
    }
    if constexpr (kind == 0)      ap_rx<TB0>(sx, sy, c, s);
    else if constexpr (kind == 1) ap_ry<TB0>(sx, sy, c, s);
    else if constexpr (kind == 2) ap_rz<TB0>(sx, sy, c, s);
    else if constexpr (kind == 3) ap_cnot<TB0, TB1>(sx, sy);
    else if constexpr (kind == 4) ap_crx<TB0, TB1>(sx, sy, c, s);
    else if constexpr (kind == 5) ap_h<TB0>(sx, sy);
    else                          ap_sxg<TB0>(sx, sy);
    apply_range<G + 1, GEND>(sx, sy, rp, rx0, ry0, rz0, crx0);
  }
}

// ===================== per-element helpers ==================================
__device__ __forceinline__ void phase1(const float* __restrict__ features,
                                       long long b, float (&t01x)[4],
                                       float (&t01y)[4], float (&t23x)[4],
                                       float (&t23y)[4]) {
  const float4* fp = (const float4*)(features + b * 16);
  float4 F0 = fp[0], F1 = fp[1], F2 = fp[2], F3 = fp[3];
  float L0[4] = {F0.x, F0.y, F0.z, F0.w};
  float L1[4] = {F1.x, F1.y, F1.z, F1.w};
  float L2[4] = {F2.x, F2.y, F2.z, F2.w};
  float L3[4] = {F3.x, F3.y, F3.z, F3.w};
  float vax[4], vay[4], vbx[4], vby[4];
#pragma unroll
  for (int w = 0; w < 4; ++w) {
    float h0 = 0.5f * L0[w], h1 = 0.5f * L1[w];
    float h2 = 0.5f * L2[w], h3 = 0.5f * L3[w];
    float s0 = __sinf(h0), c0 = __cosf(h0);
    float s1 = __sinf(h1), c1 = __cosf(h1);
    float s2 = __sinf(h2), c2 = __cosf(h2);
    float s3 = __sinf(h3), c3 = __cosf(h3);
    float ax = c0 * c1, ay = -c0 * s1;
    float bx = s0 * c1, by = s0 * s1;
    float a2x = c2 * ax + s2 * by, a2y = c2 * ay - s2 * bx;
    float b2x = s2 * ay + c2 * bx, b2y = -s2 * ax + c2 * by;
    vax[w] = c3 * a2x - s3 * b2x; vay[w] = c3 * a2y - s3 * b2y;
    vbx[w] = s3 * a2x + c3 * b2x; vby[w] = s3 * a2y + c3 * b2y;
  }
  t01x[0] = vax[0] * vax[1] - vay[0] * vay[1]; t01y[0] = vax[0] * vay[1] + vay[0] * vax[1];
  t01x[1] = vax[0] * vbx[1] - vay[0] * vby[1]; t01y[1] = vax[0] * vby[1] + vay[0] * vbx[1];
  t01x[2] = vbx[0] * vax[1] - vby[0] * vay[1]; t01y[2] = vbx[0] * vay[1] + vby[0] * vax[1];
  t01x[3] = vbx[0] * vbx[1] - vby[0] * vby[1]; t01y[3] = vbx[0] * vby[1] + vby[0] * vbx[1];
  t23x[0] = vax[2] * vax[3] - vay[2] * vay[3]; t23y[0] = vax[2] * vay[3] + vay[2] * vax[3];
  t23x[1] = vax[2] * vbx[3] - vay[2] * vby[3]; t23y[1] = vax[2] * vby[3] + vay[2] * vbx[3];
  t23x[2] = vbx[2] * vax[3] - vby[2] * vay[3]; t23y[2] = vbx[2] * vay[3] + vby[2] * vax[3];
  t23x[3] = vbx[2] * vbx[3] - vby[2] * vby[3]; t23y[3] = vbx[2] * vby[3] + vby[2] * vbx[3];
}

// phase 2: PK-packed complex matvec. All row indices compile-time (wave-
// uniform U addresses -> s_load). Two accumulators/row halve the dep chain.
// sv = s; nv = (-im, re) so U*s = sv*u.re + nv*u.im as float2 ops.
__device__ __forceinline__ void phase2_pk(const float4* __restrict__ U4,
                                          const float (&t01x)[4], const float (&t01y)[4],
                                          const float (&t23x)[4], const float (&t23y)[4],
                                          float (&ez)[4]) {
  float2 sv[16], nv[16];
#pragma unroll
  for (int i = 0; i < 16; ++i) {
    int a = i >> 2, c = i & 3;
    float sxv = t01x[a] * t23x[c] - t01y[a] * t23y[c];
    float syv = t01x[a] * t23y[c] + t01y[a] * t23x[c];
    sv[i] = make_float2(sxv, syv);
    nv[i] = make_float2(-syv, sxv);
  }
  float e0 = 0.f, e1 = 0.f, e2 = 0.f, e3 = 0.f;
#pragma unroll
  for (int i = 0; i < 16; ++i) {
    float2 a0 = make_float2(0.f, 0.f), a1 = make_float2(0.f, 0.f);
#pragma unroll
    for (int j2 = 0; j2 < 8; j2 += 2) {
      float4 u0 = U4[i * 8 + j2];       // (re0, im0, re1, im1), uniform
      float4 u1 = U4[i * 8 + j2 + 1];
      int j = 2 * j2;
      a0 = a0 + sv[j] * u0.x + nv[j] * u0.y + sv[j + 1] * u0.z + nv[j + 1] * u0.w;
      a1 = a1 + sv[j + 2] * u1.x + nv[j + 2] * u1.y + sv[j + 3] * u1.z +
           nv[j + 3] * u1.w;
    }
    float2 a = a0 + a1;
    float p = a.x * a.x + a.y * a.y;
    e0 += (i & 8) ? -p : p;
    e1 += (i & 4) ? -p : p;
    e2 += (i & 2) ? -p : p;
    e3 += (i & 1) ? -p : p;
  }
  ez[0] = e0; ez[1] = e1; ez[2] = e2; ez[3] = e3;
}

// =================== K_A: build U once (1 block, 4 waves) ===================
__global__ __launch_bounds__(256) void build_u_kernel(
    const float* __restrict__ rand_params, const float* __restrict__ rx0,
    const float* __restrict__ ry0, const float* __restrict__ rz0,
    const float* __restrict__ crx0, float2* __restrict__ U_out) {
  __shared__ float2 chunks[4][256];
  __shared__ float2 comb[2][256];
  int tid = threadIdx.x;
  int wv = tid >> 6, lane = tid & 63;

  if (lane < 16) {
    float sx[16], sy[16];
#pragma unroll
    for (int i = 0; i < 16; ++i) { sx[i] = (i == lane) ? 1.f : 0.f; sy[i] = 0.f; }
    if (wv == 0)      apply_range<0,   CK1  >(sx, sy, rand_params, rx0, ry0, rz0, crx0);
    else if (wv == 1) apply_range<CK1, CK2  >(sx, sy, rand_params, rx0, ry0, rz0, crx0);
    else if (wv == 2) apply_range<CK2, CK3  >(sx, sy, rand_params, rx0, ry0, rz0, crx0);
    else              apply_range<CK3, GL.ng>(sx, sy, rand_params, rx0, ry0, rz0, crx0);
#pragma unroll
    for (int i = 0; i < 16; ++i)
      chunks[wv][i * 16 + lane] = make_float2(sx[i], sy[i]);
  }
  __syncthreads();

  {
    int r = tid >> 4, c = tid & 15;
    float xr = 0.f, xi = 0.f, yr = 0.f, yi = 0.f;
#pragma unroll
    for (int k = 0; k < 16; ++k) {
      float2 g1 = chunks[1][r * 16 + k], g0 = chunks[0][k * 16 + c];
      xr += g1.x * g0.x - g1.y * g0.y;  xi += g1.x * g0.y + g1.y * g0.x;
      float2 g3 = chunks[3][r * 16 + k], g2 = chunks[2][k * 16 + c];
      yr += g3.x * g2.x - g3.y * g2.y;  yi += g3.x * g2.y + g3.y * g2.x;
    }
    comb[0][r * 16 + c] = make_float2(xr, xi);
    comb[1][r * 16 + c] = make_float2(yr, yi);
  }
  __syncthreads();

  {
    int r = tid >> 4, c = tid & 15;
    float ur = 0.f, ui = 0.f;
#pragma unroll
    for (int k = 0; k < 16; ++k) {
      float2 a = comb[1][r * 16 + k], d = comb[0][k * 16 + c];
      ur += a.x * d.x - a.y * d.y;
      ui += a.x * d.y + a.y * d.x;
    }
    U_out[r * 16 + c] = make_float2(ur, ui);
  }
}

// ============== K_B: encoder + pk matvec + ez + block partials ==============
__global__ __launch_bounds__(256) void main_kernel(
    const float* __restrict__ features, const float4* __restrict__ U4,
    float* __restrict__ ez_out, float* __restrict__ partials, int B, int useEz) {
  __shared__ float wred[4][8];
  int tid = threadIdx.x;

  long long b = (long long)blockIdx.x * 256 + tid;
  bool valid = b < B;
  float ez[4] = {0.f, 0.f, 0.f, 0.f};
  if (valid) {
    float t01x[4], t01y[4], t23x[4], t23y[4];
    phase1(features, b, t01x, t01y, t23x, t23y);
    phase2_pk(U4, t01x, t01y, t23x, t23y, ez);
    if (useEz) ((float4*)ez_out)[b] = make_float4(ez[0], ez[1], ez[2], ez[3]);
  }
  float q[8] = {ez[0], ez[1], ez[2], ez[3],
                ez[0] * ez[0], ez[1] * ez[1], ez[2] * ez[2], ez[3] * ez[3]};
#pragma unroll
  for (int off = 32; off; off >>= 1)
#pragma unroll
    for (int k = 0; k < 8; ++k) q[k] += __shfl_down(q[k], off, 64);
  int lane = tid & 63, wv = tid >> 6;
  if (lane == 0)
#pragma unroll
    for (int k = 0; k < 8; ++k) wred[wv][k] = q[k];
  __syncthreads();
  if (tid == 0) {
#pragma unroll
    for (int k = 0; k < 8; ++k)
      partials[(size_t)blockIdx.x * 8 + k] =
          wred[0][k] + wred[1][k] + wred[2][k] + wred[3][k];
  }
}

// ========= K_C: redundant stats reduce -> coefs -> output pass ==============
__global__ __launch_bounds__(256) void out_kernel(
    const float* __restrict__ partials, int nblk,
    const float* __restrict__ gamma, const float* __restrict__ beta,
    const float* __restrict__ W, const float* __restrict__ bias,
    const float* __restrict__ ez_in, const float* __restrict__ features,
    const float4* __restrict__ U4, float* __restrict__ out,
    int B, int useEz, float invB) {
  __shared__ float wred[4][8];
  __shared__ float coefs[5];
  int tid = threadIdx.x;

  float q[8] = {0.f, 0.f, 0.f, 0.f, 0.f, 0.f, 0.f, 0.f};
  for (int idx = tid; idx < nblk; idx += 256) {
    const float4* p4 = (const float4*)(partials + (size_t)idx * 8);
    float4 A = p4[0], Bq = p4[1];
    q[0] += A.x;  q[1] += A.y;  q[2] += A.z;  q[3] += A.w;
    q[4] += Bq.x; q[5] += Bq.y; q[6] += Bq.z; q[7] += Bq.w;
  }
#pragma unroll
  for (int off = 32; off; off >>= 1)
#pragma unroll
    for (int k = 0; k < 8; ++k) q[k] += __shfl_down(q[k], off, 64);
  int lane = tid & 63, wv = tid >> 6;
  if (lane == 0)
#pragma unroll
    for (int k = 0; k < 8; ++k) wred[wv][k] = q[k];
  __syncthreads();
  if (tid == 0) {
    float c0 = bias[0];
#pragma unroll
    for (int w = 0; w < 4; ++w) {
      float Sw = wred[0][w] + wred[1][w] + wred[2][w] + wred[3][w];
      float Qw = wred[0][4 + w] + wred[1][4 + w] + wred[2][4 + w] + wred[3][4 + w];
      float mu = Sw * invB;
      float var = Qw * invB - mu * mu;
      float inv = rsqrtf(var + 1e-5f);
      coefs[w] = W[w] * gamma[w] * inv;
      c0 += W[w] * (beta[w] - gamma[w] * mu * inv);
    }
    coefs[4] = c0;
  }
  __syncthreads();

  long long b = (long long)blockIdx.x * 256 + tid;
  if (b >= B) return;
  float ez[4];
  if (useEz) {
    float4 e = ((const float4*)ez_in)[b];
    ez[0] = e.x; ez[1] = e.y; ez[2] = e.z; ez[3] = e.w;
  } else {
    float t01x[4], t01y[4], t23x[4], t23y[4];
    phase1(features, b, t01x, t01y, t23x, t23y);
    phase2_pk(U4, t01x, t01y, t23x, t23y, ez);
  }
  out[b] = coefs[4] + coefs[0] * ez[0] + coefs[1] * ez[1] +
           coefs[2] * ez[2] + coefs[3] * ez[3];
}

// ================================ launch ====================================
extern "C" void kernel_launch(void* const* d_in, const int* in_sizes, int n_in,
                              void* d_out, int out_size, void* d_ws, size_t ws_size,
                              hipStream_t stream) {
  const float* features    = (const float*)d_in[0];
  const float* rand_params = (const float*)d_in[1];
  const float* rx0         = (const float*)d_in[2];
  const float* ry0         = (const float*)d_in[3];
  const float* rz0         = (const float*)d_in[4];
  const float* crx0        = (const float*)d_in[5];
  const float* gamma       = (const float*)d_in[6];
  const float* beta        = (const float*)d_in[7];
  const float* W           = (const float*)d_in[8];
  const float* bias        = (const float*)d_in[9];
  float* out = (float*)d_out;

  int B = in_sizes[0] / 16;
  int nblk = (B + 255) / 256;

  char* ws = (char*)d_ws;
  float2* U = (float2*)ws;                                    // 2048 B
  float* partials = (float*)(ws + 2048);                      // nblk*32 B
  size_t ez_off = (2048 + (size_t)nblk * 32 + 255) & ~(size_t)255;
  float* ez = (float*)(ws + ez_off);
  int useEz = (ws_size >= ez_off + (size_t)B * 16) ? 1 : 0;

  build_u_kernel<<<1, 256, 0, stream>>>(rand_params, rx0, ry0, rz0, crx0, U);
  main_kernel<<<nblk, 256, 0, stream>>>(features, (const float4*)U, ez,
                                        partials, B, useEz);
  out_kernel<<<nblk, 256, 0, stream>>>(partials, nblk, gamma, beta, W, bias,
                                       ez, features, (const float4*)U, out,
                                       B, useEz, 1.0f / (float)B);
}